// Round 1
// baseline (713.919 us; speedup 1.0000x reference)
//
#include <hip/hip_runtime.h>

#define EPS 1e-5f
typedef unsigned short u16;

__device__ __forceinline__ float bf2f(u16 h){
  return __uint_as_float(((unsigned int)h) << 16);
}
__device__ __forceinline__ u16 f2bf(float f){
  unsigned int u = __float_as_uint(f);
  u += 0x7fffu + ((u >> 16) & 1u);
  return (u16)(u >> 16);
}

// ---------------------------------------------------------------------------
// k_prep1: GN(x)->normed, GN(normed)->xr, gap (per-channel mean of normed)
// grid (8 chunks, 32 b), block 256. chunk = 4 groups = 32 channels.
// ---------------------------------------------------------------------------
__global__ __launch_bounds__(256) void k_prep1(
    const float* __restrict__ x, const float* __restrict__ gn_g, const float* __restrict__ gn_b,
    const float* __restrict__ ra_g, const float* __restrict__ ra_b,
    float* __restrict__ normed, float* __restrict__ xr, float* __restrict__ gap)
{
  int ch = blockIdx.x, b = blockIdx.y;
  int c0 = ch * 32;
  __shared__ float xs[1568], ns[1568];
  const float* xb = x + ((size_t)b * 256 + c0) * 49;
  for (int i = threadIdx.x; i < 1568; i += 256) xs[i] = xb[i];
  __syncthreads();
  int wv = threadIdx.x >> 6, lane = threadIdx.x & 63;
  const float* gsrc = xs + wv * 392;
  float* ndst = ns + wv * 392;
  float s = 0.f, ss = 0.f;
  for (int i = lane; i < 392; i += 64){ float v = gsrc[i]; s += v; ss += v * v; }
  for (int off = 32; off; off >>= 1){ s += __shfl_down(s, off); ss += __shfl_down(ss, off); }
  s = __shfl(s, 0); ss = __shfl(ss, 0);
  float m = s / 392.f, rs = rsqrtf(ss / 392.f - m * m + EPS);
  for (int i = lane; i < 392; i += 64){
    int c = c0 + wv * 8 + i / 49;
    ndst[i] = (gsrc[i] - m) * rs * gn_g[c] + gn_b[c];
  }
  __syncthreads();
  float* nb = normed + ((size_t)b * 256 + c0) * 49;
  for (int i = threadIdx.x; i < 1568; i += 256) nb[i] = ns[i];
  if (threadIdx.x < 32){
    float g2 = 0.f; const float* rp = ns + threadIdx.x * 49;
    for (int p = 0; p < 49; p++) g2 += rp[p];
    gap[(size_t)b * 256 + c0 + threadIdx.x] = g2 * (1.f / 49.f);
  }
  // xr = GN(normed) with ra scale/bias (same wave owns same group's data)
  s = 0.f; ss = 0.f;
  for (int i = lane; i < 392; i += 64){ float v = ndst[i]; s += v; ss += v * v; }
  for (int off = 32; off; off >>= 1){ s += __shfl_down(s, off); ss += __shfl_down(ss, off); }
  s = __shfl(s, 0); ss = __shfl(ss, 0);
  m = s / 392.f; rs = rsqrtf(ss / 392.f - m * m + EPS);
  float* xrb = xr + ((size_t)b * 256 + c0) * 49;
  for (int i = lane; i < 392; i += 64){
    int c = c0 + wv * 8 + i / 49;
    xrb[wv * 392 + i] = (ndst[i] - m) * rs * ra_g[c] + ra_b[c];
  }
}

// ---------------------------------------------------------------------------
// k_prep2: per batch: gates(x), tn=LN(normed), spatial branch, aw MLP
// grid 32, block 256.
// ---------------------------------------------------------------------------
__global__ __launch_bounds__(256) void k_prep2(
    const float* __restrict__ x, const float* __restrict__ normed,
    const float* __restrict__ sa_w1, const float* __restrict__ sa_b1,
    const float* __restrict__ sa_w2, const float* __restrict__ sa_b2,
    const float* __restrict__ sa_g, const float* __restrict__ sa_bb,
    const float* __restrict__ ln_g, const float* __restrict__ ln_b,
    const float* __restrict__ gate_w, const float* __restrict__ gate_b,
    const float* __restrict__ ap_w1, const float* __restrict__ ap_b1,
    const float* __restrict__ ap_w2, const float* __restrict__ ap_b2,
    const float* __restrict__ gap_g,
    float* __restrict__ tn_g, float* __restrict__ spat_g,
    float* __restrict__ gates_g, float* __restrict__ aw_g)
{
  int b = blockIdx.x, t = threadIdx.x;
  __shared__ float ns[12548];
  __shared__ float h1s[1568];
  __shared__ float mus[49], rss[49], gm[32], gr[32], lg[196];

  const float* nb = normed + (size_t)b * 12544;
  for (int i = t; i < 12544; i += 256) ns[i] = nb[i];
  // gate logits from raw x (global reads)
  const float* xb = x + (size_t)b * 12544;
  if (t < 196){
    int p = t >> 2, j = t & 3;
    float s = gate_b[j];
    const float* grow = gate_w + j * 256;
    for (int c = 0; c < 256; c++) s += xb[c * 49 + p] * grow[c];
    lg[t] = s;
  }
  __syncthreads();
  if (t < 49){
    float l0 = lg[t*4], l1 = lg[t*4+1], l2 = lg[t*4+2], l3 = lg[t*4+3];
    float mx = fmaxf(fmaxf(l0, l1), fmaxf(l2, l3));
    float e0 = __expf(l0-mx), e1 = __expf(l1-mx), e2 = __expf(l2-mx), e3 = __expf(l3-mx);
    float inv = 1.f / (e0 + e1 + e2 + e3);
    float* gg = gates_g + (size_t)b * 196;
    gg[t] = e0*inv; gg[49+t] = e1*inv; gg[98+t] = e2*inv; gg[147+t] = e3*inv;
  } else if (t >= 64 && t < 113){
    int p = t - 64;
    float s = 0.f, ss = 0.f;
    for (int c = 0; c < 256; c++){ float v = ns[c*49+p]; s += v; ss += v*v; }
    float mu = s / 256.f;
    mus[p] = mu; rss[p] = rsqrtf(ss / 256.f - mu*mu + EPS);
  }
  __syncthreads();
  // tn write (channel-major [b][c][p])
  float* tb = tn_g + (size_t)b * 12544;
  for (int i = t; i < 12544; i += 256){
    int c = i / 49, p = i - c * 49;
    tb[i] = (ns[i] - mus[p]) * rss[p] * ln_g[c] + ln_b[c];
  }
  // h1 = relu(sa_w1 @ normed + b1) per position
  for (int it = t; it < 1568; it += 256){
    int p = it >> 5, o = it & 31;
    float s = sa_b1[o];
    const float* wr = sa_w1 + o * 256;
    for (int c = 0; c < 256; c++) s += ns[c*49+p] * wr[c];
    h1s[p*32+o] = fmaxf(s, 0.f);
  }
  __syncthreads();
  // tmp = normed*(1+sigmoid(sa_w2 @ h1 + b2)) in place
  for (int i = t; i < 12544; i += 256){
    int c = i / 49, p = i - c * 49;
    float s = sa_b2[c];
    const float* wr = sa_w2 + c * 32;
    const float* hp = h1s + p * 32;
    #pragma unroll
    for (int o = 0; o < 32; o++) s += hp[o] * wr[o];
    float w = 1.f / (1.f + __expf(-s));
    ns[i] = ns[i] * (1.f + w);
  }
  __syncthreads();
  // GN(tmp) stats: wave wv handles groups wv, wv+4, ...
  {
    int wv = t >> 6, lane = t & 63;
    for (int g = wv; g < 32; g += 4){
      float s = 0.f, ss = 0.f;
      const float* gp = ns + g * 392;
      for (int i = lane; i < 392; i += 64){ float v = gp[i]; s += v; ss += v*v; }
      for (int off = 32; off; off >>= 1){ s += __shfl_down(s, off); ss += __shfl_down(ss, off); }
      if (lane == 0){ float m = s / 392.f; gm[g] = m; gr[g] = rsqrtf(ss / 392.f - m*m + EPS); }
    }
  }
  __syncthreads();
  float* sb = spat_g + (size_t)b * 12544;
  for (int i = t; i < 12544; i += 256){
    int c = i / 49, g = c >> 3;
    sb[i] = (ns[i] - gm[g]) * gr[g] * sa_g[c] + sa_bb[c];
  }
  // aw MLP: gap -> 128 relu -> 16 softmax
  const float* gp2 = gap_g + (size_t)b * 256;
  if (t < 128){
    float s = ap_b1[t];
    const float* wr = ap_w1 + t * 256;
    for (int c = 0; c < 256; c++) s += gp2[c] * wr[c];
    h1s[t] = fmaxf(s, 0.f);
  }
  __syncthreads();
  if (t < 16){
    float s = ap_b2[t];
    const float* wr = ap_w2 + t * 128;
    for (int o = 0; o < 128; o++) s += h1s[o] * wr[o];
    lg[t] = s;
  }
  __syncthreads();
  if (t == 0){
    float mx = -1e30f;
    for (int k = 0; k < 16; k++) mx = fmaxf(mx, lg[k]);
    float e[16], sm = 0.f;
    for (int k = 0; k < 16; k++){ e[k] = __expf(lg[k] - mx); sm += e[k]; }
    float inv = 1.f / sm;
    for (int k = 0; k < 16; k++) aw_g[b * 16 + k] = e[k] * inv;
  }
}

// ---------------------------------------------------------------------------
// k_weff: Weff[b, j] = sum_k aw[b,k] * W[k, j]  (bf16 out), j = co*6400+ci*25+s
// grid 1600, block 256; each thread owns 4 consecutive j.
// ---------------------------------------------------------------------------
__global__ __launch_bounds__(256) void k_weff(
    const float* __restrict__ W, const float* __restrict__ aw, u16* __restrict__ weff)
{
  __shared__ float aws[512];
  for (int i = threadIdx.x; i < 512; i += 256) aws[i] = aw[i];
  size_t j = (size_t)blockIdx.x * 1024 + (size_t)threadIdx.x * 4;
  float4 wv[16];
  #pragma unroll
  for (int k = 0; k < 16; k++)
    wv[k] = *(const float4*)(W + (size_t)k * 1638400 + j);
  __syncthreads();
  #pragma unroll 1
  for (int b = 0; b < 32; b++){
    const float* a = aws + b * 16;
    float a0 = 0.f, a1 = 0.f, a2 = 0.f, a3 = 0.f;
    #pragma unroll
    for (int k = 0; k < 16; k++){
      float s = a[k];
      a0 += s * wv[k].x; a1 += s * wv[k].y; a2 += s * wv[k].z; a3 += s * wv[k].w;
    }
    ushort4 o;
    o.x = f2bf(a0); o.y = f2bf(a1); o.z = f2bf(a2); o.w = f2bf(a3);
    *(ushort4*)(weff + (size_t)b * 1638400 + j) = o;
  }
}

// ---------------------------------------------------------------------------
// k_conv: per-batch 5x5 conv with Weff, ci split 16 ways -> partials
// grid (16 parts, 32 b), block 256 (thread = co). partials [part][b][co][p]
// ---------------------------------------------------------------------------
__global__ __launch_bounds__(256) void k_conv(
    const u16* __restrict__ weff, const float* __restrict__ normed, float* __restrict__ comb_part)
{
  int part = blockIdx.x, b = blockIdx.y;
  int co = threadIdx.x;
  __shared__ float xs[784];
  const float* nb = normed + ((size_t)b * 256 + part * 16) * 49;
  for (int i = co; i < 784; i += 256) xs[i] = nb[i];
  __syncthreads();
  float acc[49];
  #pragma unroll
  for (int p = 0; p < 49; p++) acc[p] = 0.f;
  const u16* wr = weff + (size_t)b * 1638400 + (size_t)co * 6400 + part * 400;
  #pragma unroll 1
  for (int ci = 0; ci < 16; ci++){
    float ximg[49];
    #pragma unroll
    for (int p = 0; p < 49; p++) ximg[p] = xs[ci * 49 + p];
    float wv[25];
    #pragma unroll
    for (int s2 = 0; s2 < 25; s2++) wv[s2] = bf2f(wr[ci * 25 + s2]);
    #pragma unroll
    for (int sy = 0; sy < 5; sy++){
      #pragma unroll
      for (int sx = 0; sx < 5; sx++){
        float w = wv[sy * 5 + sx];
        #pragma unroll
        for (int py = 0; py < 7; py++){
          int iy = py + sy - 2;
          if (iy < 0 || iy >= 7) continue;
          #pragma unroll
          for (int px = 0; px < 7; px++){
            int ix = px + sx - 2;
            if (ix < 0 || ix >= 7) continue;
            acc[py * 7 + px] += w * ximg[iy * 7 + ix];
          }
        }
      }
    }
  }
  float* op = comb_part + (((size_t)part * 32 + b) * 256 + co) * 49;
  #pragma unroll
  for (int p = 0; p < 49; p++) op[p] = acc[p];
}

__global__ __launch_bounds__(256) void k_comb_reduce(
    const float* __restrict__ part, float* __restrict__ comb)
{
  int i = blockIdx.x * 256 + threadIdx.x;
  if (i >= 100352) return;
  float a0 = 0.f, a1 = 0.f, a2 = 0.f, a3 = 0.f;
  #pragma unroll
  for (int p = 0; p < 16; p++){
    float4 v = ((const float4*)part)[(size_t)p * 100352 + i];
    a0 += v.x; a1 += v.y; a2 += v.z; a3 += v.w;
  }
  float4 o; o.x = a0; o.y = a1; o.z = a2; o.w = a3;
  ((float4*)comb)[i] = o;
}

// ---------------------------------------------------------------------------
// k_c1: generic 1x1 conv  out[b,m,p] = sum_k Wm[m,k]*act[b,k,p] (+bias)(+res)
// grid (Mtot/64, B), block 256 = 64 m x 4 p-groups.
// ---------------------------------------------------------------------------
template<int K>
__global__ __launch_bounds__(256) void k_c1(
    const float* __restrict__ Wm, const float* __restrict__ bias,
    const float* __restrict__ act, const float* __restrict__ res,
    float* __restrict__ out, int Mtot)
{
  __shared__ float as_[64 * 49 + 4];
  __shared__ float ws_[64 * 65];
  int b = blockIdx.y, m0 = blockIdx.x * 64;
  int mi = threadIdx.x >> 2, pg = threadIdx.x & 3;
  float acc[13];
  #pragma unroll
  for (int j = 0; j < 13; j++) acc[j] = 0.f;
  const float* ab = act + (size_t)b * K * 49;
  for (int kc = 0; kc < K; kc += 64){
    __syncthreads();
    for (int i = threadIdx.x; i < 64 * 49; i += 256) as_[i] = ab[kc * 49 + i];
    for (int i = threadIdx.x; i < 64 * 64; i += 256){
      int r = i >> 6, c2 = i & 63;
      ws_[r * 65 + c2] = Wm[(size_t)(m0 + r) * K + kc + c2];
    }
    __syncthreads();
    #pragma unroll 4
    for (int k2 = 0; k2 < 64; k2++){
      float wv = ws_[mi * 65 + k2];
      int base = k2 * 49 + pg;
      #pragma unroll
      for (int j = 0; j < 13; j++) acc[j] += wv * as_[base + 4 * j];
    }
  }
  int m = m0 + mi;
  float bv = bias ? bias[m] : 0.f;
  #pragma unroll
  for (int j = 0; j < 13; j++){
    int p = pg + 4 * j;
    if (p < 49){
      size_t idx = ((size_t)b * Mtot + m) * 49 + p;
      float v = acc[j] + bv;
      if (res) v += res[idx];
      out[idx] = v;
    }
  }
}

// ---------------------------------------------------------------------------
// k_attn_ra: per (head,b): d=32 attention over 49 tokens (no bias)
// ---------------------------------------------------------------------------
__global__ __launch_bounds__(256) void k_attn_ra(
    const float* __restrict__ qkv, float* __restrict__ r0)
{
  int hd = blockIdx.x, b = blockIdx.y;
  __shared__ float qs[49 * 33], ks[49 * 33], vs[49 * 33], sc[49 * 52];
  const float* base = qkv + (size_t)b * 768 * 49;
  for (int i = threadIdx.x; i < 1568; i += 256){
    int d = i / 49, tok = i - d * 49;
    qs[tok * 33 + d] = base[(hd * 32 + d) * 49 + tok];
    ks[tok * 33 + d] = base[(256 + hd * 32 + d) * 49 + tok];
    vs[tok * 33 + d] = base[(512 + hd * 32 + d) * 49 + tok];
  }
  __syncthreads();
  const float scale = 0.17677669529663687f; // 32^-0.5
  for (int it = threadIdx.x; it < 2401; it += 256){
    int i = it / 49, j = it - i * 49;
    float s = 0.f;
    #pragma unroll
    for (int d = 0; d < 32; d++) s += qs[i * 33 + d] * ks[j * 33 + d];
    sc[i * 52 + j] = s * scale;
  }
  __syncthreads();
  if (threadIdx.x < 49){
    int i = threadIdx.x;
    float mx = -1e30f;
    for (int j = 0; j < 49; j++) mx = fmaxf(mx, sc[i * 52 + j]);
    float sm = 0.f;
    for (int j = 0; j < 49; j++){ float e = __expf(sc[i * 52 + j] - mx); sc[i * 52 + j] = e; sm += e; }
    float inv = 1.f / sm;
    for (int j = 0; j < 49; j++) sc[i * 52 + j] *= inv;
  }
  __syncthreads();
  for (int it = threadIdx.x; it < 1568; it += 256){
    int d = it / 49, i = it - d * 49;
    float o = 0.f;
    for (int j = 0; j < 49; j++) o += sc[i * 52 + j] * vs[j * 33 + d];
    r0[((size_t)b * 256 + hd * 32 + d) * 49 + i] = o;
  }
}

// ---------------------------------------------------------------------------
// k_attn_aa: per (head,b): d=64 attention over 49 tokens with rel-pos bias
// ---------------------------------------------------------------------------
__global__ __launch_bounds__(256) void k_attn_aa(
    const float* __restrict__ qkv, const float* __restrict__ relpos, float* __restrict__ ao)
{
  int hd = blockIdx.x, b = blockIdx.y;
  __shared__ float qs[49 * 65], ks[49 * 65], vs[49 * 65], sc[49 * 52];
  const float* base = qkv + (size_t)b * 1536 * 49;
  for (int i = threadIdx.x; i < 3136; i += 256){
    int d = i / 49, tok = i - d * 49;
    qs[tok * 65 + d] = base[(hd * 64 + d) * 49 + tok];
    ks[tok * 65 + d] = base[(512 + hd * 64 + d) * 49 + tok];
    vs[tok * 65 + d] = base[(1024 + hd * 64 + d) * 49 + tok];
  }
  __syncthreads();
  for (int it = threadIdx.x; it < 2401; it += 256){
    int i = it / 49, j = it - i * 49;
    float s = 0.f;
    #pragma unroll
    for (int d = 0; d < 64; d++) s += qs[i * 65 + d] * ks[j * 65 + d];
    int dy = j / 7 - i / 7 + 6, dx = j % 7 - i % 7 + 6;
    sc[i * 52 + j] = s * 0.125f + relpos[(dy * 13 + dx) * 8 + hd];
  }
  __syncthreads();
  if (threadIdx.x < 49){
    int i = threadIdx.x;
    float mx = -1e30f;
    for (int j = 0; j < 49; j++) mx = fmaxf(mx, sc[i * 52 + j]);
    float sm = 0.f;
    for (int j = 0; j < 49; j++){ float e = __expf(sc[i * 52 + j] - mx); sc[i * 52 + j] = e; sm += e; }
    float inv = 1.f / sm;
    for (int j = 0; j < 49; j++) sc[i * 52 + j] *= inv;
  }
  __syncthreads();
  for (int it = threadIdx.x; it < 3136; it += 256){
    int d = it / 49, i = it - d * 49;
    float o = 0.f;
    for (int j = 0; j < 49; j++) o += sc[i * 52 + j] * vs[j * 65 + d];
    ao[((size_t)b * 512 + hd * 64 + d) * 49 + i] = o;
  }
}

// ---------------------------------------------------------------------------
// k_fusion: fused = spatial*g0 + rot*g1 + angle*g2 + adaptive*g3
// ---------------------------------------------------------------------------
__global__ __launch_bounds__(256) void k_fusion(
    const float* __restrict__ spat, const float* __restrict__ rotf,
    const float* __restrict__ angf, const float* __restrict__ adpf,
    const float* __restrict__ gates, float* __restrict__ fused)
{
  int i = blockIdx.x * 256 + threadIdx.x;
  int b = i / 12544, r = i - b * 12544;
  int p = r % 49;
  const float* g = gates + (size_t)b * 196;
  fused[i] = spat[i] * g[p] + rotf[i] * g[49 + p] + angf[i] * g[98 + p] + adpf[i] * g[147 + p];
}

// ---------------------------------------------------------------------------
extern "C" void kernel_launch(void* const* d_in, const int* in_sizes, int n_in,
                              void* d_out, int out_size, void* d_ws, size_t ws_size,
                              hipStream_t stream)
{
  const float* x        = (const float*)d_in[0];
  const float* gn_g     = (const float*)d_in[1];
  const float* gn_b     = (const float*)d_in[2];
  const float* sa_w1    = (const float*)d_in[3];
  const float* sa_b1    = (const float*)d_in[4];
  const float* sa_w2    = (const float*)d_in[5];
  const float* sa_b2    = (const float*)d_in[6];
  const float* sa_gn_g  = (const float*)d_in[7];
  const float* sa_gn_b  = (const float*)d_in[8];
  const float* ra_gn_g  = (const float*)d_in[9];
  const float* ra_gn_b  = (const float*)d_in[10];
  const float* ra_qkv_w = (const float*)d_in[11];
  const float* ra_proj_w= (const float*)d_in[12];
  const float* ra_proj_b= (const float*)d_in[13];
  const float* aa_ln_g  = (const float*)d_in[14];
  const float* aa_ln_b  = (const float*)d_in[15];
  const float* aa_qkv_w = (const float*)d_in[16];
  const float* aa_relpos= (const float*)d_in[17];
  const float* aa_out_w = (const float*)d_in[18];
  const float* aa_out_b = (const float*)d_in[19];
  const float* ad_dir_w = (const float*)d_in[20];
  const float* ad_ap_w1 = (const float*)d_in[21];
  const float* ad_ap_b1 = (const float*)d_in[22];
  const float* ad_ap_w2 = (const float*)d_in[23];
  const float* ad_ap_b2 = (const float*)d_in[24];
  const float* ad_proj_w= (const float*)d_in[25];
  const float* ad_proj_b= (const float*)d_in[26];
  const float* gate_w   = (const float*)d_in[27];
  const float* gate_b   = (const float*)d_in[28];
  const float* proj_w   = (const float*)d_in[29];
  const float* proj_b   = (const float*)d_in[30];

  char* ws = (char*)d_ws;
  // workspace layout (bytes); total ~164.3 MB
  float* normed    = (float*)(ws + 0);
  float* xr        = (float*)(ws + 1605632);
  float* tn        = (float*)(ws + 3211264);
  float* spatial   = (float*)(ws + 4816896);
  float* rotf      = (float*)(ws + 6422528);
  float* anglef    = (float*)(ws + 8028160);
  float* adaptf    = (float*)(ws + 9633792);
  float* fused     = (float*)(ws + 11239424);
  float* r0        = (float*)(ws + 12845056);
  float* gap       = (float*)(ws + 14450688);
  float* aw        = (float*)(ws + 14483456);
  float* gates     = (float*)(ws + 14485504);
  float* ra_qkv    = (float*)(ws + 14510592);
  float* aa_qkv    = (float*)(ws + 19327488);
  float* aa_o      = (float*)(ws + 28961280);
  float* comb      = (float*)(ws + 32172544);
  float* comb_part = (float*)(ws + 33778176);
  u16*   weff      = (u16*)  (ws + 59468288);

  float* out = (float*)d_out;

  k_prep1<<<dim3(8, 32), 256, 0, stream>>>(x, gn_g, gn_b, ra_gn_g, ra_gn_b, normed, xr, gap);
  k_prep2<<<dim3(32), 256, 0, stream>>>(x, normed, sa_w1, sa_b1, sa_w2, sa_b2,
                                        sa_gn_g, sa_gn_b, aa_ln_g, aa_ln_b,
                                        gate_w, gate_b, ad_ap_w1, ad_ap_b1, ad_ap_w2, ad_ap_b2,
                                        gap, tn, spatial, gates, aw);
  k_weff<<<dim3(1600), 256, 0, stream>>>(ad_dir_w, aw, weff);
  k_conv<<<dim3(16, 32), 256, 0, stream>>>(weff, normed, comb_part);

  k_c1<256><<<dim3(12, 32), 256, 0, stream>>>(ra_qkv_w, nullptr, xr, nullptr, ra_qkv, 768);
  k_attn_ra<<<dim3(8, 32), 256, 0, stream>>>(ra_qkv, r0);
  k_c1<256><<<dim3(4, 32), 256, 0, stream>>>(ra_proj_w, ra_proj_b, r0, normed, rotf, 256);

  k_c1<256><<<dim3(24, 32), 256, 0, stream>>>(aa_qkv_w, nullptr, tn, nullptr, aa_qkv, 1536);
  k_attn_aa<<<dim3(8, 32), 256, 0, stream>>>(aa_qkv, aa_relpos, aa_o);
  k_c1<512><<<dim3(4, 32), 256, 0, stream>>>(aa_out_w, aa_out_b, aa_o, normed, anglef, 256);

  k_comb_reduce<<<dim3(392), 256, 0, stream>>>(comb_part, comb);
  k_c1<256><<<dim3(4, 32), 256, 0, stream>>>(ad_proj_w, ad_proj_b, comb, normed, adaptf, 256);

  k_fusion<<<dim3(1568), 256, 0, stream>>>(spatial, rotf, anglef, adaptf, gates, fused);
  k_c1<256><<<dim3(4, 32), 256, 0, stream>>>(proj_w, proj_b, fused, x, out, 256);
}

// Round 2
// 509.601 us; speedup vs baseline: 1.4009x; 1.4009x over previous
//
#include <hip/hip_runtime.h>

#define EPS 1e-5f
typedef unsigned short u16;

__device__ __forceinline__ float bf2f(u16 h){
  return __uint_as_float(((unsigned int)h) << 16);
}
__device__ __forceinline__ u16 f2bf(float f){
  unsigned int u = __float_as_uint(f);
  u += 0x7fffu + ((u >> 16) & 1u);
  return (u16)(u >> 16);
}

// ---------------------------------------------------------------------------
// k_prep1: GN(x)->normed, GN(normed)->xr, gap (per-channel mean of normed)
// grid (8 chunks, 32 b), block 256. chunk = 4 groups = 32 channels.
// ---------------------------------------------------------------------------
__global__ __launch_bounds__(256) void k_prep1(
    const float* __restrict__ x, const float* __restrict__ gn_g, const float* __restrict__ gn_b,
    const float* __restrict__ ra_g, const float* __restrict__ ra_b,
    float* __restrict__ normed, float* __restrict__ xr, float* __restrict__ gap)
{
  int ch = blockIdx.x, b = blockIdx.y;
  int c0 = ch * 32;
  __shared__ float xs[1568], ns[1568];
  const float* xb = x + ((size_t)b * 256 + c0) * 49;
  for (int i = threadIdx.x; i < 1568; i += 256) xs[i] = xb[i];
  __syncthreads();
  int wv = threadIdx.x >> 6, lane = threadIdx.x & 63;
  const float* gsrc = xs + wv * 392;
  float* ndst = ns + wv * 392;
  float s = 0.f, ss = 0.f;
  for (int i = lane; i < 392; i += 64){ float v = gsrc[i]; s += v; ss += v * v; }
  for (int off = 32; off; off >>= 1){ s += __shfl_down(s, off); ss += __shfl_down(ss, off); }
  s = __shfl(s, 0); ss = __shfl(ss, 0);
  float m = s / 392.f, rs = rsqrtf(ss / 392.f - m * m + EPS);
  for (int i = lane; i < 392; i += 64){
    int c = c0 + wv * 8 + i / 49;
    ndst[i] = (gsrc[i] - m) * rs * gn_g[c] + gn_b[c];
  }
  __syncthreads();
  float* nb = normed + ((size_t)b * 256 + c0) * 49;
  for (int i = threadIdx.x; i < 1568; i += 256) nb[i] = ns[i];
  if (threadIdx.x < 32){
    float g2 = 0.f; const float* rp = ns + threadIdx.x * 49;
    for (int p = 0; p < 49; p++) g2 += rp[p];
    gap[(size_t)b * 256 + c0 + threadIdx.x] = g2 * (1.f / 49.f);
  }
  // xr = GN(normed) with ra scale/bias (same wave owns same group's data)
  s = 0.f; ss = 0.f;
  for (int i = lane; i < 392; i += 64){ float v = ndst[i]; s += v; ss += v * v; }
  for (int off = 32; off; off >>= 1){ s += __shfl_down(s, off); ss += __shfl_down(ss, off); }
  s = __shfl(s, 0); ss = __shfl(ss, 0);
  m = s / 392.f; rs = rsqrtf(ss / 392.f - m * m + EPS);
  float* xrb = xr + ((size_t)b * 256 + c0) * 49;
  for (int i = lane; i < 392; i += 64){
    int c = c0 + wv * 8 + i / 49;
    xrb[wv * 392 + i] = (ndst[i] - m) * rs * ra_g[c] + ra_b[c];
  }
}

// ---------------------------------------------------------------------------
// k_prep2: per batch: gates(x), tn=LN(normed), spatial branch, aw MLP
// grid 32, block 256.
// ---------------------------------------------------------------------------
__global__ __launch_bounds__(256) void k_prep2(
    const float* __restrict__ x, const float* __restrict__ normed,
    const float* __restrict__ sa_w1, const float* __restrict__ sa_b1,
    const float* __restrict__ sa_w2, const float* __restrict__ sa_b2,
    const float* __restrict__ sa_g, const float* __restrict__ sa_bb,
    const float* __restrict__ ln_g, const float* __restrict__ ln_b,
    const float* __restrict__ gate_w, const float* __restrict__ gate_b,
    const float* __restrict__ ap_w1, const float* __restrict__ ap_b1,
    const float* __restrict__ ap_w2, const float* __restrict__ ap_b2,
    const float* __restrict__ gap_g,
    float* __restrict__ tn_g, float* __restrict__ spat_g,
    float* __restrict__ gates_g, float* __restrict__ aw_g)
{
  int b = blockIdx.x, t = threadIdx.x;
  __shared__ float ns[12548];
  __shared__ float h1s[1568];
  __shared__ float mus[49], rss[49], gm[32], gr[32], lg[196];

  const float* nb = normed + (size_t)b * 12544;
  for (int i = t; i < 12544; i += 256) ns[i] = nb[i];
  // gate logits from raw x (global reads)
  const float* xb = x + (size_t)b * 12544;
  if (t < 196){
    int p = t >> 2, j = t & 3;
    float s = gate_b[j];
    const float* grow = gate_w + j * 256;
    for (int c = 0; c < 256; c++) s += xb[c * 49 + p] * grow[c];
    lg[t] = s;
  }
  __syncthreads();
  if (t < 49){
    float l0 = lg[t*4], l1 = lg[t*4+1], l2 = lg[t*4+2], l3 = lg[t*4+3];
    float mx = fmaxf(fmaxf(l0, l1), fmaxf(l2, l3));
    float e0 = __expf(l0-mx), e1 = __expf(l1-mx), e2 = __expf(l2-mx), e3 = __expf(l3-mx);
    float inv = 1.f / (e0 + e1 + e2 + e3);
    float* gg = gates_g + (size_t)b * 196;
    gg[t] = e0*inv; gg[49+t] = e1*inv; gg[98+t] = e2*inv; gg[147+t] = e3*inv;
  } else if (t >= 64 && t < 113){
    int p = t - 64;
    float s = 0.f, ss = 0.f;
    for (int c = 0; c < 256; c++){ float v = ns[c*49+p]; s += v; ss += v*v; }
    float mu = s / 256.f;
    mus[p] = mu; rss[p] = rsqrtf(ss / 256.f - mu*mu + EPS);
  }
  __syncthreads();
  // tn write (channel-major [b][c][p])
  float* tb = tn_g + (size_t)b * 12544;
  for (int i = t; i < 12544; i += 256){
    int c = i / 49, p = i - c * 49;
    tb[i] = (ns[i] - mus[p]) * rss[p] * ln_g[c] + ln_b[c];
  }
  // h1 = relu(sa_w1 @ normed + b1) per position
  for (int it = t; it < 1568; it += 256){
    int p = it >> 5, o = it & 31;
    float s = sa_b1[o];
    const float* wr = sa_w1 + o * 256;
    for (int c = 0; c < 256; c++) s += ns[c*49+p] * wr[c];
    h1s[p*32+o] = fmaxf(s, 0.f);
  }
  __syncthreads();
  // tmp = normed*(1+sigmoid(sa_w2 @ h1 + b2)) in place
  for (int i = t; i < 12544; i += 256){
    int c = i / 49, p = i - c * 49;
    float s = sa_b2[c];
    const float* wr = sa_w2 + c * 32;
    const float* hp = h1s + p * 32;
    #pragma unroll
    for (int o = 0; o < 32; o++) s += hp[o] * wr[o];
    float w = 1.f / (1.f + __expf(-s));
    ns[i] = ns[i] * (1.f + w);
  }
  __syncthreads();
  // GN(tmp) stats: wave wv handles groups wv, wv+4, ...
  {
    int wv = t >> 6, lane = t & 63;
    for (int g = wv; g < 32; g += 4){
      float s = 0.f, ss = 0.f;
      const float* gp = ns + g * 392;
      for (int i = lane; i < 392; i += 64){ float v = gp[i]; s += v; ss += v*v; }
      for (int off = 32; off; off >>= 1){ s += __shfl_down(s, off); ss += __shfl_down(ss, off); }
      if (lane == 0){ float m = s / 392.f; gm[g] = m; gr[g] = rsqrtf(ss / 392.f - m*m + EPS); }
    }
  }
  __syncthreads();
  float* sb = spat_g + (size_t)b * 12544;
  for (int i = t; i < 12544; i += 256){
    int c = i / 49, g = c >> 3;
    sb[i] = (ns[i] - gm[g]) * gr[g] * sa_g[c] + sa_bb[c];
  }
  // aw MLP: gap -> 128 relu -> 16 softmax
  const float* gp2 = gap_g + (size_t)b * 256;
  if (t < 128){
    float s = ap_b1[t];
    const float* wr = ap_w1 + t * 256;
    for (int c = 0; c < 256; c++) s += gp2[c] * wr[c];
    h1s[t] = fmaxf(s, 0.f);
  }
  __syncthreads();
  if (t < 16){
    float s = ap_b2[t];
    const float* wr = ap_w2 + t * 128;
    for (int o = 0; o < 128; o++) s += h1s[o] * wr[o];
    lg[t] = s;
  }
  __syncthreads();
  if (t == 0){
    float mx = -1e30f;
    for (int k = 0; k < 16; k++) mx = fmaxf(mx, lg[k]);
    float e[16], sm = 0.f;
    for (int k = 0; k < 16; k++){ e[k] = __expf(lg[k] - mx); sm += e[k]; }
    float inv = 1.f / sm;
    for (int k = 0; k < 16; k++) aw_g[b * 16 + k] = e[k] * inv;
  }
}

// ---------------------------------------------------------------------------
// k_weff: Weff[b, j] = sum_k aw[b,k] * W[k, j]  (bf16 out)
// ---------------------------------------------------------------------------
__global__ __launch_bounds__(256) void k_weff(
    const float* __restrict__ W, const float* __restrict__ aw, u16* __restrict__ weff)
{
  __shared__ float aws[512];
  for (int i = threadIdx.x; i < 512; i += 256) aws[i] = aw[i];
  size_t j = (size_t)blockIdx.x * 1024 + (size_t)threadIdx.x * 4;
  float4 wv[16];
  #pragma unroll
  for (int k = 0; k < 16; k++)
    wv[k] = *(const float4*)(W + (size_t)k * 1638400 + j);
  __syncthreads();
  #pragma unroll 1
  for (int b = 0; b < 32; b++){
    const float* a = aws + b * 16;
    float a0 = 0.f, a1 = 0.f, a2 = 0.f, a3 = 0.f;
    #pragma unroll
    for (int k = 0; k < 16; k++){
      float s = a[k];
      a0 += s * wv[k].x; a1 += s * wv[k].y; a2 += s * wv[k].z; a3 += s * wv[k].w;
    }
    ushort4 o;
    o.x = f2bf(a0); o.y = f2bf(a1); o.z = f2bf(a2); o.w = f2bf(a3);
    *(ushort4*)(weff + (size_t)b * 1638400 + j) = o;
  }
}

// ---------------------------------------------------------------------------
// k_conv: per-batch 5x5 conv with Weff, ci split 16 ways -> partials
// ---------------------------------------------------------------------------
__global__ __launch_bounds__(256) void k_conv(
    const u16* __restrict__ weff, const float* __restrict__ normed, float* __restrict__ comb_part)
{
  int part = blockIdx.x, b = blockIdx.y;
  int co = threadIdx.x;
  __shared__ float xs[784];
  const float* nb = normed + ((size_t)b * 256 + part * 16) * 49;
  for (int i = co; i < 784; i += 256) xs[i] = nb[i];
  __syncthreads();
  float acc[49];
  #pragma unroll
  for (int p = 0; p < 49; p++) acc[p] = 0.f;
  const u16* wr = weff + (size_t)b * 1638400 + (size_t)co * 6400 + part * 400;
  #pragma unroll 1
  for (int ci = 0; ci < 16; ci++){
    float ximg[49];
    #pragma unroll
    for (int p = 0; p < 49; p++) ximg[p] = xs[ci * 49 + p];
    float wv[25];
    #pragma unroll
    for (int s2 = 0; s2 < 25; s2++) wv[s2] = bf2f(wr[ci * 25 + s2]);
    #pragma unroll
    for (int sy = 0; sy < 5; sy++){
      #pragma unroll
      for (int sx = 0; sx < 5; sx++){
        float w = wv[sy * 5 + sx];
        #pragma unroll
        for (int py = 0; py < 7; py++){
          int iy = py + sy - 2;
          if (iy < 0 || iy >= 7) continue;
          #pragma unroll
          for (int px = 0; px < 7; px++){
            int ix = px + sx - 2;
            if (ix < 0 || ix >= 7) continue;
            acc[py * 7 + px] += w * ximg[iy * 7 + ix];
          }
        }
      }
    }
  }
  float* op = comb_part + (((size_t)part * 32 + b) * 256 + co) * 49;
  #pragma unroll
  for (int p = 0; p < 49; p++) op[p] = acc[p];
}

__global__ __launch_bounds__(256) void k_comb_reduce(
    const float* __restrict__ part, float* __restrict__ comb)
{
  int i = blockIdx.x * 256 + threadIdx.x;
  if (i >= 100352) return;
  float a0 = 0.f, a1 = 0.f, a2 = 0.f, a3 = 0.f;
  #pragma unroll
  for (int p = 0; p < 16; p++){
    float4 v = ((const float4*)part)[(size_t)p * 100352 + i];
    a0 += v.x; a1 += v.y; a2 += v.z; a3 += v.w;
  }
  float4 o; o.x = a0; o.y = a1; o.z = a2; o.w = a3;
  ((float4*)comb)[i] = o;
}

// ---------------------------------------------------------------------------
// gemm_dev: out[b,m,p] = sum_k W[m,k]*act[b,k,p] (+bias)(+res)
// 256 thr = 32 m-groups x 8 p-groups; thread tile 2m x 7p (p = pj + 8j).
// as_[64*56] act tile, ws_[64*66] W tile transposed [k][m] (pad 66: no bank
// conflict on store, keeps b64 alignment on read).
// ---------------------------------------------------------------------------
__device__ __forceinline__ void gemm_dev(
    const float* __restrict__ Wm, const float* __restrict__ bias,
    const float* __restrict__ act, const float* __restrict__ res,
    float* __restrict__ out, int Mtot, int K, int m0, int b,
    float* as_, float* ws_)
{
  int tid = threadIdx.x;
  int mi = tid >> 3;   // 0..31
  int pj = tid & 7;    // 0..7
  float acc0[7], acc1[7];
  #pragma unroll
  for (int j = 0; j < 7; j++){ acc0[j] = 0.f; acc1[j] = 0.f; }
  const float* ab = act + (size_t)b * K * 49;
  for (int kc = 0; kc < K; kc += 64){
    __syncthreads();
    for (int i = tid; i < 64 * 49; i += 256){
      int k = i / 49, p = i - k * 49;
      as_[k * 56 + p] = ab[(kc + k) * 49 + p];
    }
    for (int i = tid; i < 64 * 64; i += 256){
      int r = i >> 6, c = i & 63;
      ws_[c * 66 + r] = Wm[(size_t)(m0 + r) * K + kc + c];
    }
    __syncthreads();
    #pragma unroll 8
    for (int k = 0; k < 64; k++){
      float2 w2 = *(const float2*)(ws_ + k * 66 + mi * 2);
      float a[7];
      #pragma unroll
      for (int j = 0; j < 7; j++) a[j] = as_[k * 56 + pj + 8 * j];
      #pragma unroll
      for (int j = 0; j < 7; j++){
        acc0[j] += w2.x * a[j];
        acc1[j] += w2.y * a[j];
      }
    }
  }
  int m = m0 + mi * 2;
  float bv0 = bias ? bias[m] : 0.f;
  float bv1 = bias ? bias[m + 1] : 0.f;
  #pragma unroll
  for (int j = 0; j < 7; j++){
    int p = pj + 8 * j;
    if (p < 49){
      size_t i0 = ((size_t)b * Mtot + m) * 49 + p;
      size_t i1 = i0 + 49;
      float v0 = acc0[j] + bv0;
      float v1 = acc1[j] + bv1;
      if (res){ v0 += res[i0]; v1 += res[i1]; }
      out[i0] = v0;
      out[i1] = v1;
    }
  }
}

// merged qkv: blocks x<12 -> ra_qkv (M=768,K=256, act=xr), else aa_qkv (M=1536, act=tn)
__global__ __launch_bounds__(256) void k_qkv(
    const float* __restrict__ ra_w, const float* __restrict__ aa_w,
    const float* __restrict__ xr, const float* __restrict__ tn,
    float* __restrict__ ra_qkv, float* __restrict__ aa_qkv)
{
  __shared__ float as_[64 * 56];
  __shared__ float ws_[64 * 66];
  int xb2 = blockIdx.x, b = blockIdx.y;
  if (xb2 < 12)
    gemm_dev(ra_w, nullptr, xr, nullptr, ra_qkv, 768, 256, xb2 * 64, b, as_, ws_);
  else
    gemm_dev(aa_w, nullptr, tn, nullptr, aa_qkv, 1536, 256, (xb2 - 12) * 64, b, as_, ws_);
}

// merged projections: x<4 ra_proj (K=256), x<8 aa_out (K=512), else ad_proj (K=256)
__global__ __launch_bounds__(256) void k_proj3(
    const float* __restrict__ ra_pw, const float* __restrict__ ra_pb, const float* __restrict__ r0,
    const float* __restrict__ aa_ow, const float* __restrict__ aa_ob, const float* __restrict__ aa_o,
    const float* __restrict__ ad_pw, const float* __restrict__ ad_pb, const float* __restrict__ comb,
    const float* __restrict__ normed,
    float* __restrict__ rotf, float* __restrict__ angf, float* __restrict__ adpf)
{
  __shared__ float as_[64 * 56];
  __shared__ float ws_[64 * 66];
  int xb2 = blockIdx.x, b = blockIdx.y;
  if (xb2 < 4)
    gemm_dev(ra_pw, ra_pb, r0, normed, rotf, 256, 256, xb2 * 64, b, as_, ws_);
  else if (xb2 < 8)
    gemm_dev(aa_ow, aa_ob, aa_o, normed, angf, 256, 512, (xb2 - 4) * 64, b, as_, ws_);
  else
    gemm_dev(ad_pw, ad_pb, comb, normed, adpf, 256, 256, (xb2 - 8) * 64, b, as_, ws_);
}

// final: out = proj(fused) + x, with fused computed on the fly during staging
__global__ __launch_bounds__(256) void k_final(
    const float* __restrict__ proj_w, const float* __restrict__ proj_b,
    const float* __restrict__ spat, const float* __restrict__ rotf,
    const float* __restrict__ angf, const float* __restrict__ adpf,
    const float* __restrict__ gates, const float* __restrict__ x,
    float* __restrict__ out)
{
  __shared__ float as_[64 * 56];
  __shared__ float ws_[64 * 66];
  __shared__ float gs[196];
  int m0 = blockIdx.x * 64, b = blockIdx.y;
  int tid = threadIdx.x;
  int mi = tid >> 3, pj = tid & 7;
  if (tid < 196) gs[tid] = gates[(size_t)b * 196 + tid];
  float acc0[7], acc1[7];
  #pragma unroll
  for (int j = 0; j < 7; j++){ acc0[j] = 0.f; acc1[j] = 0.f; }
  size_t boff = (size_t)b * 12544;
  for (int kc = 0; kc < 256; kc += 64){
    __syncthreads();
    for (int i = tid; i < 64 * 49; i += 256){
      int k = i / 49, p = i - k * 49;
      size_t idx = boff + (size_t)(kc + k) * 49 + p;
      as_[k * 56 + p] = spat[idx] * gs[p] + rotf[idx] * gs[49 + p]
                      + angf[idx] * gs[98 + p] + adpf[idx] * gs[147 + p];
    }
    for (int i = tid; i < 64 * 64; i += 256){
      int r = i >> 6, c = i & 63;
      ws_[c * 66 + r] = proj_w[(size_t)(m0 + r) * 256 + kc + c];
    }
    __syncthreads();
    #pragma unroll 8
    for (int k = 0; k < 64; k++){
      float2 w2 = *(const float2*)(ws_ + k * 66 + mi * 2);
      float a[7];
      #pragma unroll
      for (int j = 0; j < 7; j++) a[j] = as_[k * 56 + pj + 8 * j];
      #pragma unroll
      for (int j = 0; j < 7; j++){
        acc0[j] += w2.x * a[j];
        acc1[j] += w2.y * a[j];
      }
    }
  }
  int m = m0 + mi * 2;
  float bv0 = proj_b[m], bv1 = proj_b[m + 1];
  #pragma unroll
  for (int j = 0; j < 7; j++){
    int p = pj + 8 * j;
    if (p < 49){
      size_t i0 = boff + (size_t)m * 49 + p;
      size_t i1 = i0 + 49;
      out[i0] = acc0[j] + bv0 + x[i0];
      out[i1] = acc1[j] + bv1 + x[i1];
    }
  }
}

// ---------------------------------------------------------------------------
// k_attn_ra: per (head,b): d=32 attention over 49 tokens (no bias)
// ---------------------------------------------------------------------------
__global__ __launch_bounds__(256) void k_attn_ra(
    const float* __restrict__ qkv, float* __restrict__ r0)
{
  int hd = blockIdx.x, b = blockIdx.y;
  __shared__ float qs[49 * 33], ks[49 * 33], vs[49 * 33], sc[49 * 52];
  const float* base = qkv + (size_t)b * 768 * 49;
  for (int i = threadIdx.x; i < 1568; i += 256){
    int d = i / 49, tok = i - d * 49;
    qs[tok * 33 + d] = base[(hd * 32 + d) * 49 + tok];
    ks[tok * 33 + d] = base[(256 + hd * 32 + d) * 49 + tok];
    vs[tok * 33 + d] = base[(512 + hd * 32 + d) * 49 + tok];
  }
  __syncthreads();
  const float scale = 0.17677669529663687f;
  for (int it = threadIdx.x; it < 2401; it += 256){
    int i = it / 49, j = it - i * 49;
    float s = 0.f;
    #pragma unroll
    for (int d = 0; d < 32; d++) s += qs[i * 33 + d] * ks[j * 33 + d];
    sc[i * 52 + j] = s * scale;
  }
  __syncthreads();
  if (threadIdx.x < 49){
    int i = threadIdx.x;
    float mx = -1e30f;
    for (int j = 0; j < 49; j++) mx = fmaxf(mx, sc[i * 52 + j]);
    float sm = 0.f;
    for (int j = 0; j < 49; j++){ float e = __expf(sc[i * 52 + j] - mx); sc[i * 52 + j] = e; sm += e; }
    float inv = 1.f / sm;
    for (int j = 0; j < 49; j++) sc[i * 52 + j] *= inv;
  }
  __syncthreads();
  for (int it = threadIdx.x; it < 1568; it += 256){
    int d = it / 49, i = it - d * 49;
    float o = 0.f;
    for (int j = 0; j < 49; j++) o += sc[i * 52 + j] * vs[j * 33 + d];
    r0[((size_t)b * 256 + hd * 32 + d) * 49 + i] = o;
  }
}

// ---------------------------------------------------------------------------
// k_attn_aa: per (head,b): d=64 attention over 49 tokens with rel-pos bias
// ---------------------------------------------------------------------------
__global__ __launch_bounds__(256) void k_attn_aa(
    const float* __restrict__ qkv, const float* __restrict__ relpos, float* __restrict__ ao)
{
  int hd = blockIdx.x, b = blockIdx.y;
  __shared__ float qs[49 * 65], ks[49 * 65], vs[49 * 65], sc[49 * 52];
  const float* base = qkv + (size_t)b * 1536 * 49;
  for (int i = threadIdx.x; i < 3136; i += 256){
    int d = i / 49, tok = i - d * 49;
    qs[tok * 65 + d] = base[(hd * 64 + d) * 49 + tok];
    ks[tok * 65 + d] = base[(512 + hd * 64 + d) * 49 + tok];
    vs[tok * 65 + d] = base[(1024 + hd * 64 + d) * 49 + tok];
  }
  __syncthreads();
  for (int it = threadIdx.x; it < 2401; it += 256){
    int i = it / 49, j = it - i * 49;
    float s = 0.f;
    #pragma unroll
    for (int d = 0; d < 64; d++) s += qs[i * 65 + d] * ks[j * 65 + d];
    int dy = j / 7 - i / 7 + 6, dx = j % 7 - i % 7 + 6;
    sc[i * 52 + j] = s * 0.125f + relpos[(dy * 13 + dx) * 8 + hd];
  }
  __syncthreads();
  if (threadIdx.x < 49){
    int i = threadIdx.x;
    float mx = -1e30f;
    for (int j = 0; j < 49; j++) mx = fmaxf(mx, sc[i * 52 + j]);
    float sm = 0.f;
    for (int j = 0; j < 49; j++){ float e = __expf(sc[i * 52 + j] - mx); sc[i * 52 + j] = e; sm += e; }
    float inv = 1.f / sm;
    for (int j = 0; j < 49; j++) sc[i * 52 + j] *= inv;
  }
  __syncthreads();
  for (int it = threadIdx.x; it < 3136; it += 256){
    int d = it / 49, i = it - d * 49;
    float o = 0.f;
    for (int j = 0; j < 49; j++) o += sc[i * 52 + j] * vs[j * 65 + d];
    ao[((size_t)b * 512 + hd * 64 + d) * 49 + i] = o;
  }
}

// ---------------------------------------------------------------------------
extern "C" void kernel_launch(void* const* d_in, const int* in_sizes, int n_in,
                              void* d_out, int out_size, void* d_ws, size_t ws_size,
                              hipStream_t stream)
{
  const float* x        = (const float*)d_in[0];
  const float* gn_g     = (const float*)d_in[1];
  const float* gn_b     = (const float*)d_in[2];
  const float* sa_w1    = (const float*)d_in[3];
  const float* sa_b1    = (const float*)d_in[4];
  const float* sa_w2    = (const float*)d_in[5];
  const float* sa_b2    = (const float*)d_in[6];
  const float* sa_gn_g  = (const float*)d_in[7];
  const float* sa_gn_b  = (const float*)d_in[8];
  const float* ra_gn_g  = (const float*)d_in[9];
  const float* ra_gn_b  = (const float*)d_in[10];
  const float* ra_qkv_w = (const float*)d_in[11];
  const float* ra_proj_w= (const float*)d_in[12];
  const float* ra_proj_b= (const float*)d_in[13];
  const float* aa_ln_g  = (const float*)d_in[14];
  const float* aa_ln_b  = (const float*)d_in[15];
  const float* aa_qkv_w = (const float*)d_in[16];
  const float* aa_relpos= (const float*)d_in[17];
  const float* aa_out_w = (const float*)d_in[18];
  const float* aa_out_b = (const float*)d_in[19];
  const float* ad_dir_w = (const float*)d_in[20];
  const float* ad_ap_w1 = (const float*)d_in[21];
  const float* ad_ap_b1 = (const float*)d_in[22];
  const float* ad_ap_w2 = (const float*)d_in[23];
  const float* ad_ap_b2 = (const float*)d_in[24];
  const float* ad_proj_w= (const float*)d_in[25];
  const float* ad_proj_b= (const float*)d_in[26];
  const float* gate_w   = (const float*)d_in[27];
  const float* gate_b   = (const float*)d_in[28];
  const float* proj_w   = (const float*)d_in[29];
  const float* proj_b   = (const float*)d_in[30];

  char* ws = (char*)d_ws;
  float* normed    = (float*)(ws + 0);
  float* xr        = (float*)(ws + 1605632);
  float* tn        = (float*)(ws + 3211264);
  float* spatial   = (float*)(ws + 4816896);
  float* rotf      = (float*)(ws + 6422528);
  float* anglef    = (float*)(ws + 8028160);
  float* adaptf    = (float*)(ws + 9633792);
  float* r0        = (float*)(ws + 12845056);
  float* gap       = (float*)(ws + 14450688);
  float* aw        = (float*)(ws + 14483456);
  float* gates     = (float*)(ws + 14485504);
  float* ra_qkv    = (float*)(ws + 14510592);
  float* aa_qkv    = (float*)(ws + 19327488);
  float* aa_o      = (float*)(ws + 28961280);
  float* comb      = (float*)(ws + 32172544);
  float* comb_part = (float*)(ws + 33778176);
  u16*   weff      = (u16*)  (ws + 59468288);

  float* out = (float*)d_out;

  k_prep1<<<dim3(8, 32), 256, 0, stream>>>(x, gn_g, gn_b, ra_gn_g, ra_gn_b, normed, xr, gap);
  k_prep2<<<dim3(32), 256, 0, stream>>>(x, normed, sa_w1, sa_b1, sa_w2, sa_b2,
                                        sa_gn_g, sa_gn_b, aa_ln_g, aa_ln_b,
                                        gate_w, gate_b, ad_ap_w1, ad_ap_b1, ad_ap_w2, ad_ap_b2,
                                        gap, tn, spatial, gates, aw);
  k_qkv<<<dim3(36, 32), 256, 0, stream>>>(ra_qkv_w, aa_qkv_w, xr, tn, ra_qkv, aa_qkv);
  k_attn_ra<<<dim3(8, 32), 256, 0, stream>>>(ra_qkv, r0);
  k_attn_aa<<<dim3(8, 32), 256, 0, stream>>>(aa_qkv, aa_relpos, aa_o);
  k_weff<<<dim3(1600), 256, 0, stream>>>(ad_dir_w, aw, weff);
  k_conv<<<dim3(16, 32), 256, 0, stream>>>(weff, normed, comb_part);
  k_comb_reduce<<<dim3(392), 256, 0, stream>>>(comb_part, comb);
  k_proj3<<<dim3(12, 32), 256, 0, stream>>>(ra_proj_w, ra_proj_b, r0,
                                            aa_out_w, aa_out_b, aa_o,
                                            ad_proj_w, ad_proj_b, comb,
                                            normed, rotf, anglef, adaptf);
  k_final<<<dim3(4, 32), 256, 0, stream>>>(proj_w, proj_b, spatial, rotf, anglef, adaptf,
                                           gates, x, out);
}

// Round 3
// 452.552 us; speedup vs baseline: 1.5775x; 1.1261x over previous
//
#include <hip/hip_runtime.h>

#define EPS 1e-5f
typedef unsigned short u16;

__device__ __forceinline__ float bf2f(u16 h){
  return __uint_as_float(((unsigned int)h) << 16);
}
__device__ __forceinline__ u16 f2bf(float f){
  unsigned int u = __float_as_uint(f);
  u += 0x7fffu + ((u >> 16) & 1u);
  return (u16)(u >> 16);
}

// ---------------------------------------------------------------------------
// k_prep1: GN(x)->normed, GN(normed)->xr, gap (per-channel mean of normed)
// grid (8 chunks, 32 b), block 256. chunk = 4 groups = 32 channels.
// ---------------------------------------------------------------------------
__global__ __launch_bounds__(256) void k_prep1(
    const float* __restrict__ x, const float* __restrict__ gn_g, const float* __restrict__ gn_b,
    const float* __restrict__ ra_g, const float* __restrict__ ra_b,
    float* __restrict__ normed, float* __restrict__ xr, float* __restrict__ gap)
{
  int ch = blockIdx.x, b = blockIdx.y;
  int c0 = ch * 32;
  __shared__ float xs[1568], ns[1568];
  const float* xb = x + ((size_t)b * 256 + c0) * 49;
  for (int i = threadIdx.x; i < 1568; i += 256) xs[i] = xb[i];
  __syncthreads();
  int wv = threadIdx.x >> 6, lane = threadIdx.x & 63;
  const float* gsrc = xs + wv * 392;
  float* ndst = ns + wv * 392;
  float s = 0.f, ss = 0.f;
  for (int i = lane; i < 392; i += 64){ float v = gsrc[i]; s += v; ss += v * v; }
  for (int off = 32; off; off >>= 1){ s += __shfl_down(s, off); ss += __shfl_down(ss, off); }
  s = __shfl(s, 0); ss = __shfl(ss, 0);
  float m = s / 392.f, rs = rsqrtf(ss / 392.f - m * m + EPS);
  for (int i = lane; i < 392; i += 64){
    int c = c0 + wv * 8 + i / 49;
    ndst[i] = (gsrc[i] - m) * rs * gn_g[c] + gn_b[c];
  }
  __syncthreads();
  float* nb = normed + ((size_t)b * 256 + c0) * 49;
  for (int i = threadIdx.x; i < 1568; i += 256) nb[i] = ns[i];
  if (threadIdx.x < 32){
    float g2 = 0.f; const float* rp = ns + threadIdx.x * 49;
    for (int p = 0; p < 49; p++) g2 += rp[p];
    gap[(size_t)b * 256 + c0 + threadIdx.x] = g2 * (1.f / 49.f);
  }
  // xr = GN(normed) with ra scale/bias (same wave owns same group's data)
  s = 0.f; ss = 0.f;
  for (int i = lane; i < 392; i += 64){ float v = ndst[i]; s += v; ss += v * v; }
  for (int off = 32; off; off >>= 1){ s += __shfl_down(s, off); ss += __shfl_down(ss, off); }
  s = __shfl(s, 0); ss = __shfl(ss, 0);
  m = s / 392.f; rs = rsqrtf(ss / 392.f - m * m + EPS);
  float* xrb = xr + ((size_t)b * 256 + c0) * 49;
  for (int i = lane; i < 392; i += 64){
    int c = c0 + wv * 8 + i / 49;
    xrb[wv * 392 + i] = (ndst[i] - m) * rs * ra_g[c] + ra_b[c];
  }
}

// ---------------------------------------------------------------------------
// k_pos: per-(b,p) LN stats (over 256 c) + gate softmax. grid(7,32), block 256.
// wave per position; lanes split channels; shuffle reduce.
// ---------------------------------------------------------------------------
__global__ __launch_bounds__(256) void k_pos(
    const float* __restrict__ x, const float* __restrict__ normed,
    const float* __restrict__ gate_w, const float* __restrict__ gate_b,
    float* __restrict__ gates_g, float* __restrict__ lnm_g, float* __restrict__ lnr_g)
{
  int pc = blockIdx.x, b = blockIdx.y;
  __shared__ float gw[1024];
  for (int i = threadIdx.x; i < 1024; i += 256) gw[i] = gate_w[i];
  __syncthreads();
  int wv = threadIdx.x >> 6, lane = threadIdx.x & 63;
  for (int pi = wv; pi < 7; pi += 4){
    int p = pc * 7 + pi;
    const float* nb = normed + (size_t)b * 12544 + p;
    const float* xb = x + (size_t)b * 12544 + p;
    float s = 0.f, ss = 0.f, g0 = 0.f, g1 = 0.f, g2 = 0.f, g3 = 0.f;
    for (int c = lane; c < 256; c += 64){
      float nv = nb[c * 49];
      float xv = xb[c * 49];
      s += nv; ss += nv * nv;
      g0 += xv * gw[c]; g1 += xv * gw[256 + c];
      g2 += xv * gw[512 + c]; g3 += xv * gw[768 + c];
    }
    for (int off = 32; off; off >>= 1){
      s += __shfl_down(s, off); ss += __shfl_down(ss, off);
      g0 += __shfl_down(g0, off); g1 += __shfl_down(g1, off);
      g2 += __shfl_down(g2, off); g3 += __shfl_down(g3, off);
    }
    if (lane == 0){
      float mu = s / 256.f;
      lnm_g[b * 49 + p] = mu;
      lnr_g[b * 49 + p] = rsqrtf(ss / 256.f - mu * mu + EPS);
      g0 += gate_b[0]; g1 += gate_b[1]; g2 += gate_b[2]; g3 += gate_b[3];
      float mx = fmaxf(fmaxf(g0, g1), fmaxf(g2, g3));
      float e0 = __expf(g0 - mx), e1 = __expf(g1 - mx), e2 = __expf(g2 - mx), e3 = __expf(g3 - mx);
      float inv = 1.f / (e0 + e1 + e2 + e3);
      float* gg = gates_g + (size_t)b * 196 + p;
      gg[0] = e0 * inv; gg[49] = e1 * inv; gg[98] = e2 * inv; gg[147] = e3 * inv;
    }
  }
}

// ---------------------------------------------------------------------------
// k_h1aw: x<7 -> h1[b,p,32] for 7 positions (LDS GEMM); x==7 -> aw MLP.
// grid(8,32), block 256.
// ---------------------------------------------------------------------------
__global__ __launch_bounds__(256) void k_h1aw(
    const float* __restrict__ normed, const float* __restrict__ sa_w1, const float* __restrict__ sa_b1,
    const float* __restrict__ ap_w1, const float* __restrict__ ap_b1,
    const float* __restrict__ ap_w2, const float* __restrict__ ap_b2,
    const float* __restrict__ gap_g,
    float* __restrict__ h1_g, float* __restrict__ aw_g)
{
  int xb2 = blockIdx.x, b = blockIdx.y;
  int t = threadIdx.x;
  if (xb2 == 7){
    __shared__ float gaps[256], h[128], lg[16];
    gaps[t] = gap_g[b * 256 + t];
    __syncthreads();
    if (t < 128){
      float s = ap_b1[t];
      const float* wr = ap_w1 + t * 256;
      #pragma unroll 4
      for (int c = 0; c < 256; c++) s += gaps[c] * wr[c];
      h[t] = fmaxf(s, 0.f);
    }
    __syncthreads();
    if (t < 16){
      float s = ap_b2[t];
      const float* wr = ap_w2 + t * 128;
      #pragma unroll 4
      for (int o = 0; o < 128; o++) s += h[o] * wr[o];
      lg[t] = s;
    }
    __syncthreads();
    if (t == 0){
      float mx = -1e30f;
      for (int k = 0; k < 16; k++) mx = fmaxf(mx, lg[k]);
      float e[16], sm = 0.f;
      for (int k = 0; k < 16; k++){ e[k] = __expf(lg[k] - mx); sm += e[k]; }
      float inv = 1.f / sm;
      for (int k = 0; k < 16; k++) aw_g[b * 16 + k] = e[k] * inv;
    }
    return;
  }
  __shared__ float w1t[256 * 33];  // [c][o], pad 33
  __shared__ float ns2[256 * 7];   // [c][pl]
  int p0 = xb2 * 7;
  for (int i = t; i < 8192; i += 256){
    int o = i >> 8, c = i & 255;
    w1t[c * 33 + o] = sa_w1[i];
  }
  for (int i = t; i < 1792; i += 256){
    int c = i / 7, pl = i - c * 7;
    ns2[i] = normed[(size_t)b * 12544 + c * 49 + p0 + pl];
  }
  __syncthreads();
  if (t < 224){
    int pl = t >> 5, o = t & 31;
    float s = sa_b1[o];
    #pragma unroll 8
    for (int c = 0; c < 256; c++) s += ns2[c * 7 + pl] * w1t[c * 33 + o];
    h1_g[(size_t)b * 1568 + (p0 + pl) * 32 + o] = fmaxf(s, 0.f);
  }
}

// ---------------------------------------------------------------------------
// k_spatial: tmp = normed*(1+sigmoid(w2@h1+b2)); GN(tmp) -> spatial.
// grid(8,32) block 256; wave = one GN group (8 ch x 49 p).
// ---------------------------------------------------------------------------
__global__ __launch_bounds__(256) void k_spatial(
    const float* __restrict__ normed, const float* __restrict__ h1_g,
    const float* __restrict__ sa_w2, const float* __restrict__ sa_b2,
    const float* __restrict__ sa_g, const float* __restrict__ sa_bb,
    float* __restrict__ spat_g)
{
  int gc = blockIdx.x, b = blockIdx.y;
  __shared__ float h1s[49 * 33];
  __shared__ float w2s[1024];
  int t = threadIdx.x;
  for (int i = t; i < 1568; i += 256){
    int p = i >> 5, o = i & 31;
    h1s[p * 33 + o] = h1_g[(size_t)b * 1568 + i];
  }
  for (int i = t; i < 1024; i += 256) w2s[i] = sa_w2[gc * 1024 + i];
  __syncthreads();
  int wv = t >> 6, lane = t & 63;
  int cg0 = wv * 8;  // local channel base within 32-ch chunk
  const float* nb = normed + (size_t)b * 12544 + (gc * 32 + cg0) * 49;
  float tmp[7];
  float s = 0.f, ss = 0.f;
  #pragma unroll
  for (int j = 0; j < 7; j++){
    int i = lane + 64 * j;
    float v = 0.f;
    if (i < 392){
      int c = i / 49;
      const float* wr = w2s + (cg0 + c) * 32;
      const float* hp = h1s + (i - c * 49) * 33;
      float d = sa_b2[gc * 32 + cg0 + c];
      #pragma unroll
      for (int o = 0; o < 32; o++) d += hp[o] * wr[o];
      v = nb[i] * (1.f + 1.f / (1.f + __expf(-d)));
      s += v; ss += v * v;
    }
    tmp[j] = v;
  }
  for (int off = 32; off; off >>= 1){ s += __shfl_down(s, off); ss += __shfl_down(ss, off); }
  s = __shfl(s, 0); ss = __shfl(ss, 0);
  float m = s / 392.f, rs = rsqrtf(ss / 392.f - m * m + EPS);
  float* sb = spat_g + (size_t)b * 12544 + (gc * 32 + cg0) * 49;
  #pragma unroll
  for (int j = 0; j < 7; j++){
    int i = lane + 64 * j;
    if (i < 392){
      int c = gc * 32 + cg0 + i / 49;
      sb[i] = (tmp[j] - m) * rs * sa_g[c] + sa_bb[c];
    }
  }
}

// ---------------------------------------------------------------------------
// k_weff: Weff[b, j] = sum_k aw[b,k] * W[k, j]  (bf16 out)
// ---------------------------------------------------------------------------
__global__ __launch_bounds__(256) void k_weff(
    const float* __restrict__ W, const float* __restrict__ aw, u16* __restrict__ weff)
{
  __shared__ float aws[512];
  for (int i = threadIdx.x; i < 512; i += 256) aws[i] = aw[i];
  size_t j = (size_t)blockIdx.x * 1024 + (size_t)threadIdx.x * 4;
  float4 wv[16];
  #pragma unroll
  for (int k = 0; k < 16; k++)
    wv[k] = *(const float4*)(W + (size_t)k * 1638400 + j);
  __syncthreads();
  #pragma unroll 1
  for (int b = 0; b < 32; b++){
    const float* a = aws + b * 16;
    float a0 = 0.f, a1 = 0.f, a2 = 0.f, a3 = 0.f;
    #pragma unroll
    for (int k = 0; k < 16; k++){
      float s = a[k];
      a0 += s * wv[k].x; a1 += s * wv[k].y; a2 += s * wv[k].z; a3 += s * wv[k].w;
    }
    ushort4 o;
    o.x = f2bf(a0); o.y = f2bf(a1); o.z = f2bf(a2); o.w = f2bf(a3);
    *(ushort4*)(weff + (size_t)b * 1638400 + j) = o;
  }
}

// ---------------------------------------------------------------------------
// k_conv: per-batch 5x5 conv with Weff, ci split 16 ways -> partials
// ---------------------------------------------------------------------------
__global__ __launch_bounds__(256) void k_conv(
    const u16* __restrict__ weff, const float* __restrict__ normed, float* __restrict__ comb_part)
{
  int part = blockIdx.x, b = blockIdx.y;
  int co = threadIdx.x;
  __shared__ float xs[784];
  const float* nb = normed + ((size_t)b * 256 + part * 16) * 49;
  for (int i = co; i < 784; i += 256) xs[i] = nb[i];
  __syncthreads();
  float acc[49];
  #pragma unroll
  for (int p = 0; p < 49; p++) acc[p] = 0.f;
  const u16* wr = weff + (size_t)b * 1638400 + (size_t)co * 6400 + part * 400;
  #pragma unroll 1
  for (int ci = 0; ci < 16; ci++){
    float ximg[49];
    #pragma unroll
    for (int p = 0; p < 49; p++) ximg[p] = xs[ci * 49 + p];
    float wv[25];
    #pragma unroll
    for (int s2 = 0; s2 < 25; s2++) wv[s2] = bf2f(wr[ci * 25 + s2]);
    #pragma unroll
    for (int sy = 0; sy < 5; sy++){
      #pragma unroll
      for (int sx = 0; sx < 5; sx++){
        float w = wv[sy * 5 + sx];
        #pragma unroll
        for (int py = 0; py < 7; py++){
          int iy = py + sy - 2;
          if (iy < 0 || iy >= 7) continue;
          #pragma unroll
          for (int px = 0; px < 7; px++){
            int ix = px + sx - 2;
            if (ix < 0 || ix >= 7) continue;
            acc[py * 7 + px] += w * ximg[iy * 7 + ix];
          }
        }
      }
    }
  }
  float* op = comb_part + (((size_t)part * 32 + b) * 256 + co) * 49;
  #pragma unroll
  for (int p = 0; p < 49; p++) op[p] = acc[p];
}

__global__ __launch_bounds__(256) void k_comb_reduce(
    const float* __restrict__ part, float* __restrict__ comb)
{
  int i = blockIdx.x * 256 + threadIdx.x;
  if (i >= 100352) return;
  float a0 = 0.f, a1 = 0.f, a2 = 0.f, a3 = 0.f;
  #pragma unroll
  for (int p = 0; p < 16; p++){
    float4 v = ((const float4*)part)[(size_t)p * 100352 + i];
    a0 += v.x; a1 += v.y; a2 += v.z; a3 += v.w;
  }
  float4 o; o.x = a0; o.y = a1; o.z = a2; o.w = a3;
  ((float4*)comb)[i] = o;
}

// ---------------------------------------------------------------------------
// gemm_dev: out[b,m,p] = sum_k W[m,k]*act'[b,k,p] (+bias)(+res)
// act' = LN(act) on the fly when lng != nullptr.
// 256 thr = 32 m-groups x 8 p-groups; thread tile 2m x 7p.
// ---------------------------------------------------------------------------
__device__ __forceinline__ void gemm_dev(
    const float* __restrict__ Wm, const float* __restrict__ bias,
    const float* __restrict__ act, const float* __restrict__ res,
    float* __restrict__ out, int Mtot, int K, int m0, int b,
    const float* __restrict__ lnm, const float* __restrict__ lnr,
    const float* __restrict__ lng, const float* __restrict__ lnb,
    float* as_, float* ws_)
{
  int tid = threadIdx.x;
  int mi = tid >> 3;   // 0..31
  int pj = tid & 7;    // 0..7
  float acc0[7], acc1[7];
  #pragma unroll
  for (int j = 0; j < 7; j++){ acc0[j] = 0.f; acc1[j] = 0.f; }
  const float* ab = act + (size_t)b * K * 49;
  for (int kc = 0; kc < K; kc += 64){
    __syncthreads();
    for (int i = tid; i < 64 * 49; i += 256){
      int k = i / 49, p = i - k * 49;
      float v = ab[(kc + k) * 49 + p];
      if (lng) v = (v - lnm[p]) * lnr[p] * lng[kc + k] + lnb[kc + k];
      as_[k * 56 + p] = v;
    }
    for (int i = tid; i < 64 * 64; i += 256){
      int r = i >> 6, c = i & 63;
      ws_[c * 66 + r] = Wm[(size_t)(m0 + r) * K + kc + c];
    }
    __syncthreads();
    #pragma unroll 8
    for (int k = 0; k < 64; k++){
      float2 w2 = *(const float2*)(ws_ + k * 66 + mi * 2);
      float a[7];
      #pragma unroll
      for (int j = 0; j < 7; j++) a[j] = as_[k * 56 + pj + 8 * j];
      #pragma unroll
      for (int j = 0; j < 7; j++){
        acc0[j] += w2.x * a[j];
        acc1[j] += w2.y * a[j];
      }
    }
  }
  int m = m0 + mi * 2;
  float bv0 = bias ? bias[m] : 0.f;
  float bv1 = bias ? bias[m + 1] : 0.f;
  #pragma unroll
  for (int j = 0; j < 7; j++){
    int p = pj + 8 * j;
    if (p < 49){
      size_t i0 = ((size_t)b * Mtot + m) * 49 + p;
      size_t i1 = i0 + 49;
      float v0 = acc0[j] + bv0;
      float v1 = acc1[j] + bv1;
      if (res){ v0 += res[i0]; v1 += res[i1]; }
      out[i0] = v0;
      out[i1] = v1;
    }
  }
}

// merged qkv: x<12 -> ra_qkv (act=xr); else aa_qkv (act=LN(normed) fused)
__global__ __launch_bounds__(256) void k_qkv(
    const float* __restrict__ ra_w, const float* __restrict__ aa_w,
    const float* __restrict__ xr, const float* __restrict__ normed,
    const float* __restrict__ lnm, const float* __restrict__ lnr,
    const float* __restrict__ ln_g, const float* __restrict__ ln_b,
    float* __restrict__ ra_qkv, float* __restrict__ aa_qkv)
{
  __shared__ float as_[64 * 56];
  __shared__ float ws_[64 * 66];
  int xb2 = blockIdx.x, b = blockIdx.y;
  if (xb2 < 12)
    gemm_dev(ra_w, nullptr, xr, nullptr, ra_qkv, 768, 256, xb2 * 64, b,
             nullptr, nullptr, nullptr, nullptr, as_, ws_);
  else
    gemm_dev(aa_w, nullptr, normed, nullptr, aa_qkv, 1536, 256, (xb2 - 12) * 64, b,
             lnm + b * 49, lnr + b * 49, ln_g, ln_b, as_, ws_);
}

// merged projections: x<4 ra_proj (K=256), x<8 aa_out (K=512), else ad_proj (K=256)
__global__ __launch_bounds__(256) void k_proj3(
    const float* __restrict__ ra_pw, const float* __restrict__ ra_pb, const float* __restrict__ r0,
    const float* __restrict__ aa_ow, const float* __restrict__ aa_ob, const float* __restrict__ aa_o,
    const float* __restrict__ ad_pw, const float* __restrict__ ad_pb, const float* __restrict__ comb,
    const float* __restrict__ normed,
    float* __restrict__ rotf, float* __restrict__ angf, float* __restrict__ adpf)
{
  __shared__ float as_[64 * 56];
  __shared__ float ws_[64 * 66];
  int xb2 = blockIdx.x, b = blockIdx.y;
  if (xb2 < 4)
    gemm_dev(ra_pw, ra_pb, r0, normed, rotf, 256, 256, xb2 * 64, b,
             nullptr, nullptr, nullptr, nullptr, as_, ws_);
  else if (xb2 < 8)
    gemm_dev(aa_ow, aa_ob, aa_o, normed, angf, 256, 512, (xb2 - 4) * 64, b,
             nullptr, nullptr, nullptr, nullptr, as_, ws_);
  else
    gemm_dev(ad_pw, ad_pb, comb, normed, adpf, 256, 256, (xb2 - 8) * 64, b,
             nullptr, nullptr, nullptr, nullptr, as_, ws_);
}

// final: out = proj(fused) + x, fused computed on the fly during staging
__global__ __launch_bounds__(256) void k_final(
    const float* __restrict__ proj_w, const float* __restrict__ proj_b,
    const float* __restrict__ spat, const float* __restrict__ rotf,
    const float* __restrict__ angf, const float* __restrict__ adpf,
    const float* __restrict__ gates, const float* __restrict__ x,
    float* __restrict__ out)
{
  __shared__ float as_[64 * 56];
  __shared__ float ws_[64 * 66];
  __shared__ float gs[196];
  int m0 = blockIdx.x * 64, b = blockIdx.y;
  int tid = threadIdx.x;
  int mi = tid >> 3, pj = tid & 7;
  if (tid < 196) gs[tid] = gates[(size_t)b * 196 + tid];
  float acc0[7], acc1[7];
  #pragma unroll
  for (int j = 0; j < 7; j++){ acc0[j] = 0.f; acc1[j] = 0.f; }
  size_t boff = (size_t)b * 12544;
  for (int kc = 0; kc < 256; kc += 64){
    __syncthreads();
    for (int i = tid; i < 64 * 49; i += 256){
      int k = i / 49, p = i - k * 49;
      size_t idx = boff + (size_t)(kc + k) * 49 + p;
      as_[k * 56 + p] = spat[idx] * gs[p] + rotf[idx] * gs[49 + p]
                      + angf[idx] * gs[98 + p] + adpf[idx] * gs[147 + p];
    }
    for (int i = tid; i < 64 * 64; i += 256){
      int r = i >> 6, c = i & 63;
      ws_[c * 66 + r] = proj_w[(size_t)(m0 + r) * 256 + kc + c];
    }
    __syncthreads();
    #pragma unroll 8
    for (int k = 0; k < 64; k++){
      float2 w2 = *(const float2*)(ws_ + k * 66 + mi * 2);
      float a[7];
      #pragma unroll
      for (int j = 0; j < 7; j++) a[j] = as_[k * 56 + pj + 8 * j];
      #pragma unroll
      for (int j = 0; j < 7; j++){
        acc0[j] += w2.x * a[j];
        acc1[j] += w2.y * a[j];
      }
    }
  }
  int m = m0 + mi * 2;
  float bv0 = proj_b[m], bv1 = proj_b[m + 1];
  #pragma unroll
  for (int j = 0; j < 7; j++){
    int p = pj + 8 * j;
    if (p < 49){
      size_t i0 = boff + (size_t)m * 49 + p;
      size_t i1 = i0 + 49;
      out[i0] = acc0[j] + bv0 + x[i0];
      out[i1] = acc1[j] + bv1 + x[i1];
    }
  }
}

// ---------------------------------------------------------------------------
// k_attn_ra: per (head,b): d=32 attention over 49 tokens (no bias)
// ---------------------------------------------------------------------------
__global__ __launch_bounds__(256) void k_attn_ra(
    const float* __restrict__ qkv, float* __restrict__ r0)
{
  int hd = blockIdx.x, b = blockIdx.y;
  __shared__ float qs[49 * 33], ks[49 * 33], vs[49 * 33], sc[49 * 52];
  const float* base = qkv + (size_t)b * 768 * 49;
  for (int i = threadIdx.x; i < 1568; i += 256){
    int d = i / 49, tok = i - d * 49;
    qs[tok * 33 + d] = base[(hd * 32 + d) * 49 + tok];
    ks[tok * 33 + d] = base[(256 + hd * 32 + d) * 49 + tok];
    vs[tok * 33 + d] = base[(512 + hd * 32 + d) * 49 + tok];
  }
  __syncthreads();
  const float scale = 0.17677669529663687f;
  for (int it = threadIdx.x; it < 2401; it += 256){
    int i = it / 49, j = it - i * 49;
    float s = 0.f;
    #pragma unroll
    for (int d = 0; d < 32; d++) s += qs[i * 33 + d] * ks[j * 33 + d];
    sc[i * 52 + j] = s * scale;
  }
  __syncthreads();
  if (threadIdx.x < 49){
    int i = threadIdx.x;
    float mx = -1e30f;
    for (int j = 0; j < 49; j++) mx = fmaxf(mx, sc[i * 52 + j]);
    float sm = 0.f;
    for (int j = 0; j < 49; j++){ float e = __expf(sc[i * 52 + j] - mx); sc[i * 52 + j] = e; sm += e; }
    float inv = 1.f / sm;
    for (int j = 0; j < 49; j++) sc[i * 52 + j] *= inv;
  }
  __syncthreads();
  for (int it = threadIdx.x; it < 1568; it += 256){
    int d = it / 49, i = it - d * 49;
    float o = 0.f;
    for (int j = 0; j < 49; j++) o += sc[i * 52 + j] * vs[j * 33 + d];
    r0[((size_t)b * 256 + hd * 32 + d) * 49 + i] = o;
  }
}

// ---------------------------------------------------------------------------
// k_attn_aa: per (head,b): d=64 attention over 49 tokens with rel-pos bias
// ---------------------------------------------------------------------------
__global__ __launch_bounds__(256) void k_attn_aa(
    const float* __restrict__ qkv, const float* __restrict__ relpos, float* __restrict__ ao)
{
  int hd = blockIdx.x, b = blockIdx.y;
  __shared__ float qs[49 * 65], ks[49 * 65], vs[49 * 65], sc[49 * 52];
  const float* base = qkv + (size_t)b * 1536 * 49;
  for (int i = threadIdx.x; i < 3136; i += 256){
    int d = i / 49, tok = i - d * 49;
    qs[tok * 65 + d] = base[(hd * 64 + d) * 49 + tok];
    ks[tok * 65 + d] = base[(512 + hd * 64 + d) * 49 + tok];
    vs[tok * 65 + d] = base[(1024 + hd * 64 + d) * 49 + tok];
  }
  __syncthreads();
  for (int it = threadIdx.x; it < 2401; it += 256){
    int i = it / 49, j = it - i * 49;
    float s = 0.f;
    #pragma unroll
    for (int d = 0; d < 64; d++) s += qs[i * 65 + d] * ks[j * 65 + d];
    int dy = j / 7 - i / 7 + 6, dx = j % 7 - i % 7 + 6;
    sc[i * 52 + j] = s * 0.125f + relpos[(dy * 13 + dx) * 8 + hd];
  }
  __syncthreads();
  if (threadIdx.x < 49){
    int i = threadIdx.x;
    float mx = -1e30f;
    for (int j = 0; j < 49; j++) mx = fmaxf(mx, sc[i * 52 + j]);
    float sm = 0.f;
    for (int j = 0; j < 49; j++){ float e = __expf(sc[i * 52 + j] - mx); sc[i * 52 + j] = e; sm += e; }
    float inv = 1.f / sm;
    for (int j = 0; j < 49; j++) sc[i * 52 + j] *= inv;
  }
  __syncthreads();
  for (int it = threadIdx.x; it < 3136; it += 256){
    int d = it / 49, i = it - d * 49;
    float o = 0.f;
    for (int j = 0; j < 49; j++) o += sc[i * 52 + j] * vs[j * 65 + d];
    ao[((size_t)b * 512 + hd * 64 + d) * 49 + i] = o;
  }
}

// ---------------------------------------------------------------------------
extern "C" void kernel_launch(void* const* d_in, const int* in_sizes, int n_in,
                              void* d_out, int out_size, void* d_ws, size_t ws_size,
                              hipStream_t stream)
{
  const float* x        = (const float*)d_in[0];
  const float* gn_g     = (const float*)d_in[1];
  const float* gn_b     = (const float*)d_in[2];
  const float* sa_w1    = (const float*)d_in[3];
  const float* sa_b1    = (const float*)d_in[4];
  const float* sa_w2    = (const float*)d_in[5];
  const float* sa_b2    = (const float*)d_in[6];
  const float* sa_gn_g  = (const float*)d_in[7];
  const float* sa_gn_b  = (const float*)d_in[8];
  const float* ra_gn_g  = (const float*)d_in[9];
  const float* ra_gn_b  = (const float*)d_in[10];
  const float* ra_qkv_w = (const float*)d_in[11];
  const float* ra_proj_w= (const float*)d_in[12];
  const float* ra_proj_b= (const float*)d_in[13];
  const float* aa_ln_g  = (const float*)d_in[14];
  const float* aa_ln_b  = (const float*)d_in[15];
  const float* aa_qkv_w = (const float*)d_in[16];
  const float* aa_relpos= (const float*)d_in[17];
  const float* aa_out_w = (const float*)d_in[18];
  const float* aa_out_b = (const float*)d_in[19];
  const float* ad_dir_w = (const float*)d_in[20];
  const float* ad_ap_w1 = (const float*)d_in[21];
  const float* ad_ap_b1 = (const float*)d_in[22];
  const float* ad_ap_w2 = (const float*)d_in[23];
  const float* ad_ap_b2 = (const float*)d_in[24];
  const float* ad_proj_w= (const float*)d_in[25];
  const float* ad_proj_b= (const float*)d_in[26];
  const float* gate_w   = (const float*)d_in[27];
  const float* gate_b   = (const float*)d_in[28];
  const float* proj_w   = (const float*)d_in[29];
  const float* proj_b   = (const float*)d_in[30];

  char* ws = (char*)d_ws;
  float* normed    = (float*)(ws + 0);
  float* xr        = (float*)(ws + 1605632);
  float* h1_g      = (float*)(ws + 3211264);   // 200704 B
  float* lnm       = (float*)(ws + 3420160);   // 6272 B
  float* lnr       = (float*)(ws + 3426560);   // 6272 B
  float* spatial   = (float*)(ws + 4816896);
  float* rotf      = (float*)(ws + 6422528);
  float* anglef    = (float*)(ws + 8028160);
  float* adaptf    = (float*)(ws + 9633792);
  float* r0        = (float*)(ws + 12845056);
  float* gap       = (float*)(ws + 14450688);
  float* aw        = (float*)(ws + 14483456);
  float* gates     = (float*)(ws + 14485504);
  float* ra_qkv    = (float*)(ws + 14510592);
  float* aa_qkv    = (float*)(ws + 19327488);
  float* aa_o      = (float*)(ws + 28961280);
  float* comb      = (float*)(ws + 32172544);
  float* comb_part = (float*)(ws + 33778176);
  u16*   weff      = (u16*)  (ws + 59468288);

  float* out = (float*)d_out;

  k_prep1<<<dim3(8, 32), 256, 0, stream>>>(x, gn_g, gn_b, ra_gn_g, ra_gn_b, normed, xr, gap);
  k_pos<<<dim3(7, 32), 256, 0, stream>>>(x, normed, gate_w, gate_b, gates, lnm, lnr);
  k_h1aw<<<dim3(8, 32), 256, 0, stream>>>(normed, sa_w1, sa_b1,
                                          ad_ap_w1, ad_ap_b1, ad_ap_w2, ad_ap_b2,
                                          gap, h1_g, aw);
  k_spatial<<<dim3(8, 32), 256, 0, stream>>>(normed, h1_g, sa_w2, sa_b2, sa_gn_g, sa_gn_b, spatial);
  k_weff<<<dim3(1600), 256, 0, stream>>>(ad_dir_w, aw, weff);
  k_qkv<<<dim3(36, 32), 256, 0, stream>>>(ra_qkv_w, aa_qkv_w, xr, normed,
                                          lnm, lnr, aa_ln_g, aa_ln_b, ra_qkv, aa_qkv);
  k_attn_ra<<<dim3(8, 32), 256, 0, stream>>>(ra_qkv, r0);
  k_attn_aa<<<dim3(8, 32), 256, 0, stream>>>(aa_qkv, aa_relpos, aa_o);
  k_conv<<<dim3(16, 32), 256, 0, stream>>>(weff, normed, comb_part);
  k_comb_reduce<<<dim3(392), 256, 0, stream>>>(comb_part, comb);
  k_proj3<<<dim3(12, 32), 256, 0, stream>>>(ra_proj_w, ra_proj_b, r0,
                                            aa_out_w, aa_out_b, aa_o,
                                            ad_proj_w, ad_proj_b, comb,
                                            normed, rotf, anglef, adaptf);
  k_final<<<dim3(4, 32), 256, 0, stream>>>(proj_w, proj_b, spatial, rotf, anglef, adaptf,
                                           gates, x, out);
}